// Round 1
// baseline (489.452 us; speedup 1.0000x reference)
//
#include <hip/hip_runtime.h>

// ---------------------------------------------------------------------------
// SelfAttention block: x @ W_qkv -> RoPE(q,k) -> flash attention -> @ W_proj
// B=2, S=2048, D=2048, H=16, hd=128.  All matmuls in bf16 MFMA (fp32 accum).
// ---------------------------------------------------------------------------

typedef __attribute__((ext_vector_type(4))) float  f32x4;
typedef __attribute__((ext_vector_type(8))) short  short8;
typedef __attribute__((ext_vector_type(4))) float  fv4;
typedef __attribute__((ext_vector_type(4))) unsigned short us4;

#define MFMA16(accv, av, bv) \
  asm volatile("v_mfma_f32_16x16x32_bf16 %0, %1, %2, %0" : "+v"(accv) : "v"(av), "v"(bv))

__device__ __forceinline__ unsigned short f2bf(float f) {
  unsigned int u = __float_as_uint(f);
  u += 0x7fffu + ((u >> 16) & 1u);      // round-to-nearest-even
  return (unsigned short)(u >> 16);
}

__device__ __forceinline__ void gl_lds16(const void* g, void* l) {
  // async global->LDS, 16B per lane; LDS dest = uniform base + lane*16
  __builtin_amdgcn_global_load_lds((const __attribute__((address_space(1))) void*)g,
                                   (__attribute__((address_space(3))) void*)l, 16, 0, 0);
}

// ---------------------------------------------------------------------------
// Prep: fp32 -> bf16 convert (x), and fp32 -> transposed bf16 (weights)
// ---------------------------------------------------------------------------
__global__ void cvt_f32_bf16(const float* __restrict__ in,
                             unsigned short* __restrict__ out, int n4) {
  int i = blockIdx.x * blockDim.x + threadIdx.x;
  int stride = gridDim.x * blockDim.x;
  for (; i < n4; i += stride) {
    fv4 v = ((const fv4*)in)[i];
    us4 o;
    o[0] = f2bf(v[0]); o[1] = f2bf(v[1]); o[2] = f2bf(v[2]); o[3] = f2bf(v[3]);
    ((us4*)out)[i] = o;
  }
}

// in: [R][C] fp32, out: [C][R] bf16
__global__ void transpose_cvt(const float* __restrict__ in,
                              unsigned short* __restrict__ out, int R, int C) {
  __shared__ float tile[32][33];
  int c0 = blockIdx.x * 32, r0 = blockIdx.y * 32;
  int tx = threadIdx.x, ty = threadIdx.y;
#pragma unroll
  for (int i = 0; i < 4; i++)
    tile[ty + i * 8][tx] = in[(size_t)(r0 + ty + i * 8) * C + c0 + tx];
  __syncthreads();
#pragma unroll
  for (int i = 0; i < 4; i++)
    out[(size_t)(c0 + ty + i * 8) * R + r0 + tx] = f2bf(tile[tx][ty + i * 8]);
}

// ---------------------------------------------------------------------------
// QKV GEMM: C[4096][6144] = xb[4096][2048] @ WqkvT[6144][2048]^T  (+bias)
// Fused epilogue: RoPE on q,k (q pre-scaled by 1/sqrt(128)), V stored
// transposed [b][h][d][s].  128x128 tile, BK=64, 2x2 waves.
// Column tiles per wave interleaved {2wc,2wc+1,2wc+4,2wc+5} so RoPE pairs
// (d, d+64) live in the same wave.
// ---------------------------------------------------------------------------
__global__ __launch_bounds__(256, 2) void qkv_gemm(
    const unsigned short* __restrict__ A,   // xb [4096][2048]
    const unsigned short* __restrict__ Bt,  // WqkvT [6144][2048]
    const float* __restrict__ bias,         // [6144]
    unsigned short* __restrict__ Qo,        // [2][16][2048][128]
    unsigned short* __restrict__ Ko,        // [2][16][2048][128]
    unsigned short* __restrict__ Vo)        // [2][16][128][2048]
{
  __shared__ __align__(16) unsigned short Al[128 * 64];
  __shared__ __align__(16) unsigned short Bl[128 * 64];

  const int NBX = 48, NWG = 1536;
  int bid = blockIdx.x;
  int nid = (bid & 7) * (NWG / 8) + (bid >> 3);   // XCD-contiguous chunks
  int by = nid / NBX, bx = nid - by * NBX;

  int tid = threadIdx.x;
  int wv = tid >> 6, lane = tid & 63;
  int wr = wv >> 1, wc = wv & 1;
  int g = lane >> 4, c = lane & 15;

  int m0 = by * 128, n0 = bx * 128;

  f32x4 acc[4][4];
#pragma unroll
  for (int m = 0; m < 4; m++)
#pragma unroll
    for (int n = 0; n < 4; n++)
#pragma unroll
      for (int r = 0; r < 4; r++) acc[m][n][r] = 0.f;

  for (int k0 = 0; k0 < 2048; k0 += 64) {
#pragma unroll
    for (int i = 0; i < 4; i++) {
      int s = wv * 256 + i * 64 + lane;
      int row = s >> 3;
      int cb = (s & 7) ^ (row & 7);     // pre-swizzled source (G21)
      gl_lds16(A  + (size_t)(m0 + row) * 2048 + k0 + cb * 8,
               Al + (size_t)(wv * 256 + i * 64) * 8);
      gl_lds16(Bt + (size_t)(n0 + row) * 2048 + k0 + cb * 8,
               Bl + (size_t)(wv * 256 + i * 64) * 8);
    }
    __syncthreads();

    short8 af[4][2], bf[4][2];
#pragma unroll
    for (int m = 0; m < 4; m++) {
      int row = wr * 64 + m * 16 + c;
#pragma unroll
      for (int kc = 0; kc < 2; kc++)
        af[m][kc] = *(const short8*)(Al + row * 64 + (((kc * 4 + g) ^ (row & 7)) * 8));
    }
#pragma unroll
    for (int n = 0; n < 4; n++) {
      int gt = 2 * wc + (n & 1) + (n >> 1) * 4;
      int row = gt * 16 + c;
#pragma unroll
      for (int kc = 0; kc < 2; kc++)
        bf[n][kc] = *(const short8*)(Bl + row * 64 + (((kc * 4 + g) ^ (row & 7)) * 8));
    }
#pragma unroll
    for (int m = 0; m < 4; m++)
#pragma unroll
      for (int n = 0; n < 4; n++) {
        MFMA16(acc[m][n], af[m][0], bf[n][0]);
        MFMA16(acc[m][n], af[m][1], bf[n][1]);
      }
    __syncthreads();
  }

  int sel = bx >> 4;   // 0=q 1=k 2=v  (block covers exactly one (sel,head))
  int h = bx & 15;
  int b = by >> 4;

  int dloc[4];
  float biasv[4];
#pragma unroll
  for (int n = 0; n < 4; n++) {
    int gt = 2 * wc + (n & 1) + (n >> 1) * 4;
    dloc[n] = gt * 16 + c;
    biasv[n] = bias[n0 + dloc[n]];
  }

  if (sel == 2) {
    // V: LDS transpose (swizzled) then coalesced store to Vo[b][h][d][s]
    unsigned short* Vs = Al;   // 128*64 ushorts, reuse staging LDS
    for (int p = 0; p < 2; p++) {
      if (wr == p) {
#pragma unroll
        for (int m = 0; m < 4; m++)
#pragma unroll
          for (int n = 0; n < 4; n++) {
            int d = dloc[n];
#pragma unroll
            for (int r = 0; r < 4; r++) {
              int srel = m * 16 + 4 * g + r;
              Vs[d * 64 + (srel ^ ((d & 7) << 3))] = f2bf(acc[m][n][r] + biasv[n]);
            }
          }
      }
      __syncthreads();
#pragma unroll
      for (int i = 0; i < 4; i++) {
        int seg = i * 256 + tid;
        int d = seg >> 3, slot = seg & 7;
        short8 val = *(const short8*)(Vs + d * 64 + ((slot ^ (d & 7)) * 8));
        int s_seq = (by & 15) * 128 + p * 64 + slot * 8;
        *(short8*)(Vo + ((size_t)((b * 16 + h) * 128 + d)) * 2048 + s_seq) = val;
      }
      __syncthreads();
    }
  } else {
    // q / k: RoPE epilogue
    unsigned short* outp = (sel == 0) ? Qo : Ko;
    float qscale = (sel == 0) ? 0.08838834764831845f : 1.0f;  // 1/sqrt(128)
    float invf[2];
#pragma unroll
    for (int j = 0; j < 2; j++)
      invf[j] = __expf(-(float)dloc[j] * 0.14391156831212787f);  // ln(1e4)/64
    int srow_base = (by & 15) * 128 + wr * 64;
#pragma unroll
    for (int m = 0; m < 4; m++) {
#pragma unroll
      for (int j = 0; j < 2; j++) {
        int dlo = dloc[j];
#pragma unroll
        for (int r = 0; r < 4; r++) {
          int s_seq = srow_base + m * 16 + 4 * g + r;
          float ang = (float)s_seq * invf[j];
          float sn, cs;
          __sincosf(ang, &sn, &cs);
          float vlo = acc[m][j][r]     + biasv[j];
          float vhi = acc[m][j + 2][r] + biasv[j + 2];
          float rlo = (vlo * cs - vhi * sn) * qscale;
          float rhi = (vhi * cs + vlo * sn) * qscale;
          size_t base = ((size_t)((b * 16 + h) * 2048 + s_seq)) * 128;
          outp[base + dlo]      = f2bf(rlo);
          outp[base + dlo + 64] = f2bf(rhi);
        }
      }
    }
  }
}

// ---------------------------------------------------------------------------
// Flash attention: per block one (b,h) x 64 q-rows; 4 waves x 16 q-rows.
// KV tiles of 32, online softmax.  Q pre-scaled, K natural, V transposed.
// ---------------------------------------------------------------------------
__global__ __launch_bounds__(256, 2) void attn_kernel(
    const unsigned short* __restrict__ Qi,   // [32][2048][128]
    const unsigned short* __restrict__ Ki,   // [32][2048][128]
    const unsigned short* __restrict__ Vi,   // [32][128][2048]
    unsigned short* __restrict__ X2)         // [4096][2048] bf16
{
  __shared__ __align__(16) unsigned short Kl[32 * 128];
  __shared__ __align__(16) unsigned short Vl[128 * 32];
  __shared__ __align__(16) unsigned short Pl[4][16 * 32];

  int bid = blockIdx.x;
  int nid = (bid & 7) * 128 + (bid >> 3);   // XCD swizzle: 4 heads' KV per L2
  int bh = nid >> 5, qt = nid & 31;
  int tid = threadIdx.x, wv = tid >> 6, lane = tid & 63;
  int g = lane >> 4, c = lane & 15;

  int q0 = qt * 64 + wv * 16;
  const unsigned short* Qb = Qi + ((size_t)bh * 2048 + q0) * 128;
  short8 qf[4];
#pragma unroll
  for (int dc = 0; dc < 4; dc++)
    qf[dc] = *(const short8*)(Qb + (size_t)c * 128 + dc * 32 + g * 8);

  f32x4 accO[8];
#pragma unroll
  for (int nt = 0; nt < 8; nt++)
#pragma unroll
    for (int r = 0; r < 4; r++) accO[nt][r] = 0.f;
  float m_run[4], l_run[4];
#pragma unroll
  for (int r = 0; r < 4; r++) { m_run[r] = -3.0e38f; l_run[r] = 0.f; }

  const unsigned short* Kg = Ki + (size_t)bh * 2048 * 128;
  const unsigned short* Vg = Vi + (size_t)bh * 128 * 2048;

  for (int t0 = 0; t0 < 2048; t0 += 32) {
#pragma unroll
    for (int i = 0; i < 2; i++) {
      int s = wv * 128 + i * 64 + lane;
      int trow = s >> 4, cb = (s & 15) ^ (trow & 7);
      gl_lds16(Kg + (size_t)(t0 + trow) * 128 + cb * 8,
               Kl + (size_t)(wv * 128 + i * 64) * 8);
      int d = s >> 2, cb2 = (s & 3) ^ (d & 3);
      gl_lds16(Vg + (size_t)d * 2048 + t0 + cb2 * 8,
               Vl + (size_t)(wv * 128 + i * 64) * 8);
    }
    __syncthreads();

    f32x4 s0, s1;
#pragma unroll
    for (int r = 0; r < 4; r++) { s0[r] = 0.f; s1[r] = 0.f; }
#pragma unroll
    for (int dc = 0; dc < 4; dc++) {
      short8 kf0 = *(const short8*)(Kl + (size_t)c * 128 + (((dc * 4 + g) ^ (c & 7)) * 8));
      short8 kf1 = *(const short8*)(Kl + (size_t)(16 + c) * 128 + (((dc * 4 + g) ^ ((16 + c) & 7)) * 8));
      MFMA16(s0, qf[dc], kf0);
      MFMA16(s1, qf[dc], kf1);
    }

    float p0[4], p1[4], alpha[4];
#pragma unroll
    for (int r = 0; r < 4; r++) {
      float mx = fmaxf(s0[r], s1[r]);
      mx = fmaxf(mx, __shfl_xor(mx, 1));
      mx = fmaxf(mx, __shfl_xor(mx, 2));
      mx = fmaxf(mx, __shfl_xor(mx, 4));
      mx = fmaxf(mx, __shfl_xor(mx, 8));
      float mnew = fmaxf(m_run[r], mx);
      alpha[r] = __expf(m_run[r] - mnew);
      p0[r] = __expf(s0[r] - mnew);
      p1[r] = __expf(s1[r] - mnew);
      float rs = p0[r] + p1[r];
      rs += __shfl_xor(rs, 1); rs += __shfl_xor(rs, 2);
      rs += __shfl_xor(rs, 4); rs += __shfl_xor(rs, 8);
      l_run[r] = l_run[r] * alpha[r] + rs;
      m_run[r] = mnew;
    }
#pragma unroll
    for (int nt = 0; nt < 8; nt++)
#pragma unroll
      for (int r = 0; r < 4; r++) accO[nt][r] *= alpha[r];

    unsigned short* Pw = Pl[wv];
#pragma unroll
    for (int r = 0; r < 4; r++) {
      Pw[(4 * g + r) * 32 + c]      = f2bf(p0[r]);
      Pw[(4 * g + r) * 32 + 16 + c] = f2bf(p1[r]);
    }
    short8 pf = *(const short8*)(Pw + c * 32 + g * 8);
#pragma unroll
    for (int nt = 0; nt < 8; nt++) {
      int d = nt * 16 + c;
      short8 vf = *(const short8*)(Vl + (size_t)d * 32 + ((g ^ (d & 3)) * 8));
      MFMA16(accO[nt], pf, vf);
    }
    __syncthreads();
  }

  float rl[4];
#pragma unroll
  for (int r = 0; r < 4; r++) rl[r] = 1.0f / l_run[r];
  int b = bh >> 4, h = bh & 15;
#pragma unroll
  for (int nt = 0; nt < 8; nt++)
#pragma unroll
    for (int r = 0; r < 4; r++) {
      int qrow = q0 + 4 * g + r;
      X2[((size_t)(b * 2048 + qrow)) * 2048 + h * 128 + nt * 16 + c] =
          f2bf(accO[nt][r] * rl[r]);
    }
}

// ---------------------------------------------------------------------------
// Proj GEMM: out[4096][2048] = x2[4096][2048] @ WprojT[2048][2048]^T + bias
// ---------------------------------------------------------------------------
__global__ __launch_bounds__(256, 2) void proj_gemm(
    const unsigned short* __restrict__ A,
    const unsigned short* __restrict__ Bt,
    const float* __restrict__ bias,
    float* __restrict__ Co)
{
  __shared__ __align__(16) unsigned short Al[128 * 64];
  __shared__ __align__(16) unsigned short Bl[128 * 64];

  const int NBX = 16, NWG = 512;
  int bid = blockIdx.x;
  int nid = (bid & 7) * (NWG / 8) + (bid >> 3);
  int by = nid / NBX, bx = nid - by * NBX;

  int tid = threadIdx.x;
  int wv = tid >> 6, lane = tid & 63;
  int wr = wv >> 1, wc = wv & 1;
  int g = lane >> 4, c = lane & 15;

  int m0 = by * 128, n0 = bx * 128;

  f32x4 acc[4][4];
#pragma unroll
  for (int m = 0; m < 4; m++)
#pragma unroll
    for (int n = 0; n < 4; n++)
#pragma unroll
      for (int r = 0; r < 4; r++) acc[m][n][r] = 0.f;

  for (int k0 = 0; k0 < 2048; k0 += 64) {
#pragma unroll
    for (int i = 0; i < 4; i++) {
      int s = wv * 256 + i * 64 + lane;
      int row = s >> 3;
      int cb = (s & 7) ^ (row & 7);
      gl_lds16(A  + (size_t)(m0 + row) * 2048 + k0 + cb * 8,
               Al + (size_t)(wv * 256 + i * 64) * 8);
      gl_lds16(Bt + (size_t)(n0 + row) * 2048 + k0 + cb * 8,
               Bl + (size_t)(wv * 256 + i * 64) * 8);
    }
    __syncthreads();

    short8 af[4][2], bf[4][2];
#pragma unroll
    for (int m = 0; m < 4; m++) {
      int row = wr * 64 + m * 16 + c;
#pragma unroll
      for (int kc = 0; kc < 2; kc++)
        af[m][kc] = *(const short8*)(Al + row * 64 + (((kc * 4 + g) ^ (row & 7)) * 8));
    }
#pragma unroll
    for (int n = 0; n < 4; n++) {
      int row = wc * 64 + n * 16 + c;
#pragma unroll
      for (int kc = 0; kc < 2; kc++)
        bf[n][kc] = *(const short8*)(Bl + row * 64 + (((kc * 4 + g) ^ (row & 7)) * 8));
    }
#pragma unroll
    for (int m = 0; m < 4; m++)
#pragma unroll
      for (int n = 0; n < 4; n++) {
        MFMA16(acc[m][n], af[m][0], bf[n][0]);
        MFMA16(acc[m][n], af[m][1], bf[n][1]);
      }
    __syncthreads();
  }

#pragma unroll
  for (int m = 0; m < 4; m++)
#pragma unroll
    for (int n = 0; n < 4; n++)
#pragma unroll
      for (int r = 0; r < 4; r++) {
        int row = m0 + wr * 64 + m * 16 + 4 * g + r;
        int col = n0 + wc * 64 + n * 16 + c;
        Co[(size_t)row * 2048 + col] = acc[m][n][r] + bias[col];
      }
}

// ---------------------------------------------------------------------------
extern "C" void kernel_launch(void* const* d_in, const int* in_sizes, int n_in,
                              void* d_out, int out_size, void* d_ws, size_t ws_size,
                              hipStream_t stream) {
  (void)in_sizes; (void)n_in; (void)out_size; (void)ws_size;

  const float* x      = (const float*)d_in[0];   // [2][2048][2048]
  const float* W_qkv  = (const float*)d_in[1];   // [2048][6144]
  const float* b_qkv  = (const float*)d_in[2];   // [6144]
  const float* W_proj = (const float*)d_in[3];   // [2048][2048]
  const float* b_proj = (const float*)d_in[4];   // [2048]
  float* out = (float*)d_out;                    // [4096][2048]

  // workspace layout (bf16 elements); total ~114 MB
  unsigned short* xb     = (unsigned short*)d_ws;     // 4096*2048
  unsigned short* wqkvT  = xb     + 8388608;          // 6144*2048
  unsigned short* wprojT = wqkvT  + 12582912;         // 2048*2048
  unsigned short* Qb     = wprojT + 4194304;          // 32*2048*128
  unsigned short* Kb     = Qb     + 8388608;
  unsigned short* Vtb    = Kb     + 8388608;          // [32][128][2048]
  unsigned short* x2     = Vtb    + 8388608;          // 4096*2048

  cvt_f32_bf16<<<2048, 256, 0, stream>>>(x, xb, 8388608 / 4);
  transpose_cvt<<<dim3(192, 64), dim3(32, 8), 0, stream>>>(W_qkv, wqkvT, 2048, 6144);
  transpose_cvt<<<dim3(64, 64),  dim3(32, 8), 0, stream>>>(W_proj, wprojT, 2048, 2048);
  qkv_gemm<<<1536, 256, 0, stream>>>(xb, wqkvT, b_qkv, Qb, Kb, Vtb);
  attn_kernel<<<1024, 256, 0, stream>>>(Qb, Kb, Vtb, x2);
  proj_gemm<<<512, 256, 0, stream>>>(x2, wprojT, b_proj, out);
}

// Round 2
// 397.583 us; speedup vs baseline: 1.2311x; 1.2311x over previous
//
#include <hip/hip_runtime.h>

// ---------------------------------------------------------------------------
// SelfAttention block: x @ W_qkv -> RoPE(q,k) -> flash attention -> @ W_proj
// B=2, S=2048, D=2048, H=16, hd=128.  All matmuls in bf16 MFMA (fp32 accum).
// ---------------------------------------------------------------------------

typedef __attribute__((ext_vector_type(4))) float  f32x4;
typedef __attribute__((ext_vector_type(8))) short  short8;
typedef __attribute__((ext_vector_type(4))) float  fv4;
typedef __attribute__((ext_vector_type(4))) unsigned short us4;

#define MFMA16(accv, av, bv) \
  asm volatile("v_mfma_f32_16x16x32_bf16 %0, %1, %2, %0" : "+v"(accv) : "v"(av), "v"(bv))

__device__ __forceinline__ unsigned short f2bf(float f) {
  unsigned int u = __float_as_uint(f);
  u += 0x7fffu + ((u >> 16) & 1u);      // round-to-nearest-even
  return (unsigned short)(u >> 16);
}

__device__ __forceinline__ void gl_lds16(const void* g, void* l) {
  // async global->LDS, 16B per lane; LDS dest = uniform base + lane*16
  __builtin_amdgcn_global_load_lds((const __attribute__((address_space(1))) void*)g,
                                   (__attribute__((address_space(3))) void*)l, 16, 0, 0);
}

// ---------------------------------------------------------------------------
// Prep: fp32 -> bf16 convert (x), and fp32 -> transposed bf16 (weights)
// ---------------------------------------------------------------------------
__global__ void cvt_f32_bf16(const float* __restrict__ in,
                             unsigned short* __restrict__ out, int n4) {
  int i = blockIdx.x * blockDim.x + threadIdx.x;
  int stride = gridDim.x * blockDim.x;
  for (; i < n4; i += stride) {
    fv4 v = ((const fv4*)in)[i];
    us4 o;
    o[0] = f2bf(v[0]); o[1] = f2bf(v[1]); o[2] = f2bf(v[2]); o[3] = f2bf(v[3]);
    ((us4*)out)[i] = o;
  }
}

// in: [R][C] fp32, out: [C][R] bf16
__global__ void transpose_cvt(const float* __restrict__ in,
                              unsigned short* __restrict__ out, int R, int C) {
  __shared__ float tile[32][33];
  int c0 = blockIdx.x * 32, r0 = blockIdx.y * 32;
  int tx = threadIdx.x, ty = threadIdx.y;
#pragma unroll
  for (int i = 0; i < 4; i++)
    tile[ty + i * 8][tx] = in[(size_t)(r0 + ty + i * 8) * C + c0 + tx];
  __syncthreads();
#pragma unroll
  for (int i = 0; i < 4; i++)
    out[(size_t)(c0 + ty + i * 8) * R + r0 + tx] = f2bf(tile[tx][ty + i * 8]);
}

// ---------------------------------------------------------------------------
// QKV GEMM: C[4096][6144] = xb[4096][2048] @ WqkvT[6144][2048]^T  (+bias)
// Fused epilogue: RoPE on q,k (q pre-scaled by log2e/sqrt(128) for exp2-domain
// softmax), V stored transposed [b][h][d][s].  128x128 tile, BK=64, 2x2 waves.
// ---------------------------------------------------------------------------
__global__ __launch_bounds__(256, 2) void qkv_gemm(
    const unsigned short* __restrict__ A,   // xb [4096][2048]
    const unsigned short* __restrict__ Bt,  // WqkvT [6144][2048]
    const float* __restrict__ bias,         // [6144]
    unsigned short* __restrict__ Qo,        // [2][16][2048][128]
    unsigned short* __restrict__ Ko,        // [2][16][2048][128]
    unsigned short* __restrict__ Vo)        // [2][16][128][2048]
{
  __shared__ __align__(16) unsigned short Al[128 * 64];
  __shared__ __align__(16) unsigned short Bl[128 * 64];

  const int NBX = 48, NWG = 1536;
  int bid = blockIdx.x;
  int nid = (bid & 7) * (NWG / 8) + (bid >> 3);   // XCD-contiguous chunks
  int by = nid / NBX, bx = nid - by * NBX;

  int tid = threadIdx.x;
  int wv = tid >> 6, lane = tid & 63;
  int wr = wv >> 1, wc = wv & 1;
  int g = lane >> 4, c = lane & 15;

  int m0 = by * 128, n0 = bx * 128;

  f32x4 acc[4][4];
#pragma unroll
  for (int m = 0; m < 4; m++)
#pragma unroll
    for (int n = 0; n < 4; n++)
#pragma unroll
      for (int r = 0; r < 4; r++) acc[m][n][r] = 0.f;

  for (int k0 = 0; k0 < 2048; k0 += 64) {
#pragma unroll
    for (int i = 0; i < 4; i++) {
      int s = wv * 256 + i * 64 + lane;
      int row = s >> 3;
      int cb = (s & 7) ^ (row & 7);     // pre-swizzled source (G21)
      gl_lds16(A  + (size_t)(m0 + row) * 2048 + k0 + cb * 8,
               Al + (size_t)(wv * 256 + i * 64) * 8);
      gl_lds16(Bt + (size_t)(n0 + row) * 2048 + k0 + cb * 8,
               Bl + (size_t)(wv * 256 + i * 64) * 8);
    }
    __syncthreads();

    short8 af[4][2], bf[4][2];
#pragma unroll
    for (int m = 0; m < 4; m++) {
      int row = wr * 64 + m * 16 + c;
#pragma unroll
      for (int kc = 0; kc < 2; kc++)
        af[m][kc] = *(const short8*)(Al + row * 64 + (((kc * 4 + g) ^ (row & 7)) * 8));
    }
#pragma unroll
    for (int n = 0; n < 4; n++) {
      int gt = 2 * wc + (n & 1) + (n >> 1) * 4;
      int row = gt * 16 + c;
#pragma unroll
      for (int kc = 0; kc < 2; kc++)
        bf[n][kc] = *(const short8*)(Bl + row * 64 + (((kc * 4 + g) ^ (row & 7)) * 8));
    }
#pragma unroll
    for (int m = 0; m < 4; m++)
#pragma unroll
      for (int n = 0; n < 4; n++) {
        MFMA16(acc[m][n], af[m][0], bf[n][0]);
        MFMA16(acc[m][n], af[m][1], bf[n][1]);
      }
    __syncthreads();
  }

  int sel = bx >> 4;   // 0=q 1=k 2=v  (block covers exactly one (sel,head))
  int h = bx & 15;
  int b = by >> 4;

  int dloc[4];
  float biasv[4];
#pragma unroll
  for (int n = 0; n < 4; n++) {
    int gt = 2 * wc + (n & 1) + (n >> 1) * 4;
    dloc[n] = gt * 16 + c;
    biasv[n] = bias[n0 + dloc[n]];
  }

  if (sel == 2) {
    // V: LDS transpose (swizzled) then coalesced store to Vo[b][h][d][s]
    unsigned short* Vs = Al;   // 128*64 ushorts, reuse staging LDS
    for (int p = 0; p < 2; p++) {
      if (wr == p) {
#pragma unroll
        for (int m = 0; m < 4; m++)
#pragma unroll
          for (int n = 0; n < 4; n++) {
            int d = dloc[n];
#pragma unroll
            for (int r = 0; r < 4; r++) {
              int srel = m * 16 + 4 * g + r;
              Vs[d * 64 + (srel ^ ((d & 7) << 3))] = f2bf(acc[m][n][r] + biasv[n]);
            }
          }
      }
      __syncthreads();
#pragma unroll
      for (int i = 0; i < 4; i++) {
        int seg = i * 256 + tid;
        int d = seg >> 3, slot = seg & 7;
        short8 val = *(const short8*)(Vs + d * 64 + ((slot ^ (d & 7)) * 8));
        int s_seq = (by & 15) * 128 + p * 64 + slot * 8;
        *(short8*)(Vo + ((size_t)((b * 16 + h) * 128 + d)) * 2048 + s_seq) = val;
      }
      __syncthreads();
    }
  } else {
    // q / k: RoPE epilogue
    unsigned short* outp = (sel == 0) ? Qo : Ko;
    // q pre-scaled by log2(e)/sqrt(128) so attention softmax runs in exp2 domain
    float qscale = (sel == 0) ? (0.08838834764831845f * 1.44269504088896340736f) : 1.0f;
    float invf[2];
#pragma unroll
    for (int j = 0; j < 2; j++)
      invf[j] = __expf(-(float)dloc[j] * 0.14391156831212787f);  // ln(1e4)/64
    int srow_base = (by & 15) * 128 + wr * 64;
#pragma unroll
    for (int m = 0; m < 4; m++) {
#pragma unroll
      for (int j = 0; j < 2; j++) {
        int dlo = dloc[j];
#pragma unroll
        for (int r = 0; r < 4; r++) {
          int s_seq = srow_base + m * 16 + 4 * g + r;
          float ang = (float)s_seq * invf[j];
          float sn, cs;
          __sincosf(ang, &sn, &cs);
          float vlo = acc[m][j][r]     + biasv[j];
          float vhi = acc[m][j + 2][r] + biasv[j + 2];
          float rlo = (vlo * cs - vhi * sn) * qscale;
          float rhi = (vhi * cs + vlo * sn) * qscale;
          size_t base = ((size_t)((b * 16 + h) * 2048 + s_seq)) * 128;
          outp[base + dlo]      = f2bf(rlo);
          outp[base + dlo + 64] = f2bf(rhi);
        }
      }
    }
  }
}

// ---------------------------------------------------------------------------
// Flash attention v2: per block one (b,h) x 128 q-rows; 4 waves x 32 q-rows.
// KVBLK=64, double-buffered K/V staging (2-phase pipeline, 1 barrier/iter).
// Swapped QK^T (mfma(K,Q)): scores land [k=4g+r][q=c] -> in-lane row max/sum,
// P packed via v_cvt_pk_bf16_f32 into swizzled per-wave LDS (conflict-free).
// exp2-domain softmax (Q pre-scaled by log2e), skip-rescale on no-growth.
// ---------------------------------------------------------------------------
__global__ __launch_bounds__(256, 2) void attn_kernel(
    const unsigned short* __restrict__ Qi,   // [32][2048][128]
    const unsigned short* __restrict__ Ki,   // [32][2048][128]
    const unsigned short* __restrict__ Vi,   // [32][128][2048]
    unsigned short* __restrict__ X2)         // [4096][2048] bf16
{
  __shared__ __align__(16) unsigned short Kl[2][64 * 128];   // [s][d], swizzled
  __shared__ __align__(16) unsigned short Vl[2][128 * 64];   // [d][s], swizzled
  __shared__ __align__(16) unsigned short Pl[4][32 * 64];    // per-wave [q][k], swizzled

  int bid = blockIdx.x;
  int nid = (bid & 7) * 64 + (bid >> 3);   // XCD swizzle: 4 heads' KV per L2
  int bh = nid >> 4, qblk = nid & 15;
  int tid = threadIdx.x, wv = tid >> 6, lane = tid & 63;
  int g = lane >> 4, c = lane & 15;

  const unsigned short* Kg = Ki + (size_t)bh * 2048 * 128;
  const unsigned short* Vg = Vi + (size_t)bh * 128 * 2048;
  const unsigned short* Qb = Qi + ((size_t)bh * 2048 + qblk * 128 + wv * 32) * 128;

  short8 qf[2][4];
#pragma unroll
  for (int qt = 0; qt < 2; qt++)
#pragma unroll
    for (int dc = 0; dc < 4; dc++)
      qf[qt][dc] = *(const short8*)(Qb + (size_t)(qt * 16 + c) * 128 + dc * 32 + g * 8);

  f32x4 accO[2][8];
#pragma unroll
  for (int qt = 0; qt < 2; qt++)
#pragma unroll
    for (int nt = 0; nt < 8; nt++)
#pragma unroll
      for (int r = 0; r < 4; r++) accO[qt][nt][r] = 0.f;
  float m_run[2] = {-3.0e38f, -3.0e38f};
  float l_run[2] = {0.f, 0.f};

  // stage one 64-row K/V tile into buffer bsel (8 x gl_lds16 per thread)
  auto stage = [&](int bsel, int t0) {
#pragma unroll
    for (int j = 0; j < 4; j++) {
      int e = j * 256 + tid;              // 0..1023
      int s = e >> 4, sl = e & 15;        // K row / 16B slot
      gl_lds16(Kg + (size_t)(t0 + s) * 128 + ((sl ^ (s & 7)) * 8),
               &Kl[bsel][(size_t)(j * 256 + wv * 64) * 8]);
    }
#pragma unroll
    for (int j = 0; j < 4; j++) {
      int e = j * 256 + tid;
      int d = e >> 3, sl = e & 7;         // V row / 16B slot
      gl_lds16(Vg + (size_t)d * 2048 + t0 + ((sl ^ (d & 7)) * 8),
               &Vl[bsel][(size_t)(j * 256 + wv * 64) * 8]);
    }
  };

  stage(0, 0);
  __syncthreads();          // compiler drains vmcnt before barrier

  int cur = 0;
  for (int t = 0; t < 32; t++) {
    if (t < 31) stage(cur ^ 1, (t + 1) * 64);   // prefetch next tile

    const unsigned short* Kt_ = &Kl[cur][0];
    const unsigned short* Vt_ = &Vl[cur][0];
    unsigned short* Pw = &Pl[wv][0];

    // ---- QK^T (swapped): sc[qt][kt] holds S[k=kt*16+4g+r][q=qt*16+c] ----
    f32x4 sc[2][4];
#pragma unroll
    for (int qt = 0; qt < 2; qt++)
#pragma unroll
      for (int kt = 0; kt < 4; kt++)
#pragma unroll
        for (int r = 0; r < 4; r++) sc[qt][kt][r] = 0.f;

#pragma unroll
    for (int kt = 0; kt < 4; kt++) {
      short8 kf[4];
#pragma unroll
      for (int dc = 0; dc < 4; dc++)
        kf[dc] = *(const short8*)(Kt_ + (size_t)(kt * 16 + c) * 128 +
                                  (((dc * 4 + g) ^ (c & 7)) * 8));
      __builtin_amdgcn_s_setprio(1);
#pragma unroll
      for (int dc = 0; dc < 4; dc++) {
        MFMA16(sc[0][kt], kf[dc], qf[0][dc]);
        MFMA16(sc[1][kt], kf[dc], qf[1][dc]);
      }
      __builtin_amdgcn_s_setprio(0);
    }

    // ---- online softmax (exp2 domain; per lane: 16 k's for q = qt*16+c) ----
    float mx[2];
#pragma unroll
    for (int qt = 0; qt < 2; qt++) {
      f32x4 mv = sc[qt][0];
#pragma unroll
      for (int kt = 1; kt < 4; kt++)
#pragma unroll
        for (int r = 0; r < 4; r++) mv[r] = fmaxf(mv[r], sc[qt][kt][r]);
      float m0 = fmaxf(fmaxf(mv[0], mv[1]), fmaxf(mv[2], mv[3]));
      m0 = fmaxf(m0, __shfl_xor(m0, 16));
      m0 = fmaxf(m0, __shfl_xor(m0, 32));
      mx[qt] = m0;
    }
    if (__any((mx[0] > m_run[0]) || (mx[1] > m_run[1]))) {
#pragma unroll
      for (int qt = 0; qt < 2; qt++) {
        float mnew = fmaxf(m_run[qt], mx[qt]);
        float al = __builtin_exp2f(m_run[qt] - mnew);
        l_run[qt] *= al;
        m_run[qt] = mnew;
#pragma unroll
        for (int r = 0; r < 4; r++) {
          float alr = __shfl(al, 4 * g + r);
#pragma unroll
          for (int nt = 0; nt < 8; nt++) accO[qt][nt][r] *= alr;
        }
      }
    }
#pragma unroll
    for (int qt = 0; qt < 2; qt++) {
      float rs = 0.f;
#pragma unroll
      for (int kt = 0; kt < 4; kt++) {
        float p0 = __builtin_exp2f(sc[qt][kt][0] - m_run[qt]);
        float p1 = __builtin_exp2f(sc[qt][kt][1] - m_run[qt]);
        float p2 = __builtin_exp2f(sc[qt][kt][2] - m_run[qt]);
        float p3 = __builtin_exp2f(sc[qt][kt][3] - m_run[qt]);
        rs += (p0 + p1) + (p2 + p3);
        unsigned int lo, hi;
        asm("v_cvt_pk_bf16_f32 %0, %1, %2" : "=v"(lo) : "v"(p0), "v"(p1));
        asm("v_cvt_pk_bf16_f32 %0, %1, %2" : "=v"(hi) : "v"(p2), "v"(p3));
        uint2 pk; pk.x = lo; pk.y = hi;
        // P[q = qt*16+c][k = kt*16+4g+r]; 16B slot = kt*2+(g>>1) ^ (c&7)
        *(uint2*)(Pw + (size_t)(qt * 16 + c) * 64 +
                  (((kt * 2 + (g >> 1)) ^ (c & 7)) * 8) + (g & 1) * 4) = pk;
      }
      rs += __shfl_xor(rs, 16);
      rs += __shfl_xor(rs, 32);
      l_run[qt] += rs;
    }

    // ---- PV: accO[qt][nt] += P[q][k] * V[k][d] ----
    short8 pa[2][2];
#pragma unroll
    for (int qt = 0; qt < 2; qt++)
#pragma unroll
      for (int kc = 0; kc < 2; kc++)
        pa[qt][kc] = *(const short8*)(Pw + (size_t)(qt * 16 + c) * 64 +
                                      (((kc * 4 + g) ^ (c & 7)) * 8));
#pragma unroll
    for (int nt = 0; nt < 8; nt++) {
      short8 vf0 = *(const short8*)(Vt_ + (size_t)(nt * 16 + c) * 64 +
                                    ((g ^ (c & 7)) * 8));
      short8 vf1 = *(const short8*)(Vt_ + (size_t)(nt * 16 + c) * 64 +
                                    (((4 + g) ^ (c & 7)) * 8));
      __builtin_amdgcn_s_setprio(1);
      MFMA16(accO[0][nt], pa[0][0], vf0);
      MFMA16(accO[1][nt], pa[1][0], vf0);
      MFMA16(accO[0][nt], pa[0][1], vf1);
      MFMA16(accO[1][nt], pa[1][1], vf1);
      __builtin_amdgcn_s_setprio(0);
    }

    __syncthreads();          // drains prefetch vmcnt -> buf[cur^1] ready
    cur ^= 1;
  }

  // ---- epilogue: normalize and store ----
  float rl[2] = {1.f / l_run[0], 1.f / l_run[1]};
  int b = bh >> 4, h = bh & 15;
  size_t rowbase = (size_t)b * 2048 + qblk * 128 + wv * 32;
#pragma unroll
  for (int qt = 0; qt < 2; qt++)
#pragma unroll
    for (int r = 0; r < 4; r++) {
      float rr = __shfl(rl[qt], 4 * g + r);
      size_t row = rowbase + qt * 16 + 4 * g + r;
#pragma unroll
      for (int nt = 0; nt < 8; nt++)
        X2[row * 2048 + h * 128 + nt * 16 + c] = f2bf(accO[qt][nt][r] * rr);
    }
}

// ---------------------------------------------------------------------------
// Proj GEMM: out[4096][2048] = x2[4096][2048] @ WprojT[2048][2048]^T + bias
// ---------------------------------------------------------------------------
__global__ __launch_bounds__(256, 2) void proj_gemm(
    const unsigned short* __restrict__ A,
    const unsigned short* __restrict__ Bt,
    const float* __restrict__ bias,
    float* __restrict__ Co)
{
  __shared__ __align__(16) unsigned short Al[128 * 64];
  __shared__ __align__(16) unsigned short Bl[128 * 64];

  const int NBX = 16, NWG = 512;
  int bid = blockIdx.x;
  int nid = (bid & 7) * (NWG / 8) + (bid >> 3);
  int by = nid / NBX, bx = nid - by * NBX;

  int tid = threadIdx.x;
  int wv = tid >> 6, lane = tid & 63;
  int wr = wv >> 1, wc = wv & 1;
  int g = lane >> 4, c = lane & 15;

  int m0 = by * 128, n0 = bx * 128;

  f32x4 acc[4][4];
#pragma unroll
  for (int m = 0; m < 4; m++)
#pragma unroll
    for (int n = 0; n < 4; n++)
#pragma unroll
      for (int r = 0; r < 4; r++) acc[m][n][r] = 0.f;

  for (int k0 = 0; k0 < 2048; k0 += 64) {
#pragma unroll
    for (int i = 0; i < 4; i++) {
      int s = wv * 256 + i * 64 + lane;
      int row = s >> 3;
      int cb = (s & 7) ^ (row & 7);
      gl_lds16(A  + (size_t)(m0 + row) * 2048 + k0 + cb * 8,
               Al + (size_t)(wv * 256 + i * 64) * 8);
      gl_lds16(Bt + (size_t)(n0 + row) * 2048 + k0 + cb * 8,
               Bl + (size_t)(wv * 256 + i * 64) * 8);
    }
    __syncthreads();

    short8 af[4][2], bf[4][2];
#pragma unroll
    for (int m = 0; m < 4; m++) {
      int row = wr * 64 + m * 16 + c;
#pragma unroll
      for (int kc = 0; kc < 2; kc++)
        af[m][kc] = *(const short8*)(Al + row * 64 + (((kc * 4 + g) ^ (row & 7)) * 8));
    }
#pragma unroll
    for (int n = 0; n < 4; n++) {
      int row = wc * 64 + n * 16 + c;
#pragma unroll
      for (int kc = 0; kc < 2; kc++)
        bf[n][kc] = *(const short8*)(Bl + row * 64 + (((kc * 4 + g) ^ (row & 7)) * 8));
    }
#pragma unroll
    for (int m = 0; m < 4; m++)
#pragma unroll
      for (int n = 0; n < 4; n++) {
        MFMA16(acc[m][n], af[m][0], bf[n][0]);
        MFMA16(acc[m][n], af[m][1], bf[n][1]);
      }
    __syncthreads();
  }

#pragma unroll
  for (int m = 0; m < 4; m++)
#pragma unroll
    for (int n = 0; n < 4; n++)
#pragma unroll
      for (int r = 0; r < 4; r++) {
        int row = m0 + wr * 64 + m * 16 + 4 * g + r;
        int col = n0 + wc * 64 + n * 16 + c;
        Co[(size_t)row * 2048 + col] = acc[m][n][r] + bias[col];
      }
}

// ---------------------------------------------------------------------------
extern "C" void kernel_launch(void* const* d_in, const int* in_sizes, int n_in,
                              void* d_out, int out_size, void* d_ws, size_t ws_size,
                              hipStream_t stream) {
  (void)in_sizes; (void)n_in; (void)out_size; (void)ws_size;

  const float* x      = (const float*)d_in[0];   // [2][2048][2048]
  const float* W_qkv  = (const float*)d_in[1];   // [2048][6144]
  const float* b_qkv  = (const float*)d_in[2];   // [6144]
  const float* W_proj = (const float*)d_in[3];   // [2048][2048]
  const float* b_proj = (const float*)d_in[4];   // [2048]
  float* out = (float*)d_out;                    // [4096][2048]

  // workspace layout (bf16 elements); total ~114 MB
  unsigned short* xb     = (unsigned short*)d_ws;     // 4096*2048
  unsigned short* wqkvT  = xb     + 8388608;          // 6144*2048
  unsigned short* wprojT = wqkvT  + 12582912;         // 2048*2048
  unsigned short* Qb     = wprojT + 4194304;          // 32*2048*128
  unsigned short* Kb     = Qb     + 8388608;
  unsigned short* Vtb    = Kb     + 8388608;          // [32][128][2048]
  unsigned short* x2     = Vtb    + 8388608;          // 4096*2048

  cvt_f32_bf16<<<2048, 256, 0, stream>>>(x, xb, 8388608 / 4);
  transpose_cvt<<<dim3(192, 64), dim3(32, 8), 0, stream>>>(W_qkv, wqkvT, 2048, 6144);
  transpose_cvt<<<dim3(64, 64),  dim3(32, 8), 0, stream>>>(W_proj, wprojT, 2048, 2048);
  qkv_gemm<<<1536, 256, 0, stream>>>(xb, wqkvT, b_qkv, Qb, Kb, Vtb);
  attn_kernel<<<512, 256, 0, stream>>>(Qb, Kb, Vtb, x2);
  proj_gemm<<<512, 256, 0, stream>>>(x2, wprojT, b_proj, out);
}